// Round 2
// baseline (419.807 us; speedup 1.0000x reference)
//
#include <hip/hip_runtime.h>

// Local2DSum: out[b,v,h,s] = log(sum_c exp(x[b,v,h,c]) * exp(acc[v,h,c,s]))
//                          - log(sum_c exp(acc[v,h,c,s]))
// B=64, V=32, H=32, C=256, S=256. Inputs N(0,1) -> exp safe in fp16.
//
// R2: 2 blocks per (v,h), each owns 128 S-columns. Software-pipelined acc
// loads (prefetch next K-chunk's registers), double-buffered Bsm with ONE
// barrier per chunk. LDS 52 KB -> 3 blocks/CU.

typedef _Float16 f16x8 __attribute__((ext_vector_type(8)));
typedef _Float16 f16x2 __attribute__((ext_vector_type(2)));
typedef float f32x4 __attribute__((ext_vector_type(4)));

constexpr int BPITCH = 40;            // f16 per Bsm row (80 B)
constexpr int BBUF   = 128 * BPITCH;  // f16 per buffer (10240 B)

__global__ __launch_bounds__(256, 3)
void logmm_kernel(const float* __restrict__ x,
                  const float* __restrict__ acc,
                  float* __restrict__ out) {
    __shared__ __align__(16) _Float16 Asm[64 * 256];   // 32 KB, exp(x) f16, swizzled
    __shared__ __align__(16) _Float16 Bsm[2 * BBUF];   // 20 KB, exp(acc)^T ping-pong

    const int tid   = threadIdx.x;        // 0..255
    const int vh    = blockIdx.x >> 1;    // 0..1023
    const int sbase = (blockIdx.x & 1) * 128;

    const float* xb = x   + (size_t)vh * 256;            // b-stride 262144
    const float* ab = acc + (size_t)vh * 65536 + sbase;  // [c][s-local]
    float*       ob = out + (size_t)vh * 256 + sbase;    // b-stride 262144

    // ---- stage A = exp(x) as f16 into LDS (once), XOR-swizzled 16B blocks ----
    {
        const int half = tid >> 7;
        const int c2   = (tid & 127) * 2;
        const int blk  = c2 >> 3;
        #pragma unroll
        for (int it = 0; it < 32; ++it) {
            int row = it * 2 + half;
            float2 v = *(const float2*)(xb + (size_t)row * 262144 + c2);
            f16x2 pk;
            pk.x = (_Float16)__expf(v.x);
            pk.y = (_Float16)__expf(v.y);
            int pb = blk ^ (row & 7);
            *(f16x2*)(Asm + row * 256 + pb * 8 + (c2 & 7)) = pk;
        }
    }

    const int w  = tid >> 6;              // wave -> s-slice base w*32
    const int l  = tid & 63;
    const int ln = l & 15;
    const int q  = l >> 4;

    const int col   = tid & 127;          // local s column this thread stages
    const int khalf = (tid >> 7) * 16;    // k sub-range 0..15 or 16..31

    f32x4 accv[4][2];
    #pragma unroll
    for (int mt = 0; mt < 4; ++mt)
        #pragma unroll
        for (int nt = 0; nt < 2; ++nt)
            accv[mt][nt] = (f32x4){0.f, 0.f, 0.f, 0.f};

    float csum = 0.f;    // partial denom for column `col` over this thread's k rows
    float cur[16], nxt[16];

    // preload chunk 0
    #pragma unroll
    for (int i = 0; i < 16; ++i)
        cur[i] = ab[(size_t)(khalf + i) * 256 + col];

    #pragma unroll
    for (int ch = 0; ch < 8; ++ch) {
        // prefetch next chunk (in flight across exp/pack/barrier/MFMA)
        if (ch < 7) {
            const int c0n = (ch + 1) * 32;
            #pragma unroll
            for (int i = 0; i < 16; ++i)
                nxt[i] = ab[(size_t)(c0n + khalf + i) * 256 + col];
        }
        // process current chunk -> Bsm[buf]
        _Float16* Bb = Bsm + (ch & 1) * BBUF;
        #pragma unroll
        for (int g = 0; g < 2; ++g) {
            f16x8 pk;
            #pragma unroll
            for (int i = 0; i < 8; ++i) {
                float e = __expf(cur[g * 8 + i]);
                csum += e;
                pk[i] = (_Float16)e;
            }
            int G  = (khalf >> 3) + g;               // logical k-group 0..3
            int pg = G ^ ((col >> 2) & 3);           // XOR swizzle
            *(f16x8*)(Bb + col * BPITCH + pg * 8) = pk;
        }
        __syncthreads();   // single barrier: writes visible; prior buf reads reg-complete
        // ---- MFMA step (K=32) ----
        f16x8 bf[2];
        #pragma unroll
        for (int nt = 0; nt < 2; ++nt) {
            int s  = w * 32 + nt * 16 + ln;
            int pg = q ^ ((s >> 2) & 3);
            bf[nt] = *(const f16x8*)(Bb + s * BPITCH + pg * 8);
        }
        f16x8 af[4];
        const int blk = ch * 4 + q;
        #pragma unroll
        for (int mt = 0; mt < 4; ++mt) {
            int r  = mt * 16 + ln;
            int pb = blk ^ (r & 7);
            af[mt] = *(const f16x8*)(Asm + r * 256 + pb * 8);
        }
        #pragma unroll
        for (int mt = 0; mt < 4; ++mt)
            #pragma unroll
            for (int nt = 0; nt < 2; ++nt)
                accv[mt][nt] = __builtin_amdgcn_mfma_f32_16x16x32_f16(
                    af[mt], bf[nt], accv[mt][nt], 0, 0, 0);
        #pragma unroll
        for (int i = 0; i < 16; ++i) cur[i] = nxt[i];
    }

    // ---- denom: reduce the two k-half partials per column, share log ----
    __syncthreads();
    float* red = (float*)Bsm;         // 256 floats
    red[tid] = csum;
    __syncthreads();
    float* lden = red + 256;          // 128 floats
    if (tid < 128) lden[tid] = __logf(red[tid] + red[tid + 128]);
    __syncthreads();

    // ---- epilogue: out = log(prod) - log(denom) ----
    // C/D layout: col s = lane&15 (+tile), row b = quad*4 + reg (+tile)
    #pragma unroll
    for (int nt = 0; nt < 2; ++nt) {
        int sl = w * 32 + nt * 16 + ln;
        float ld = lden[sl];
        #pragma unroll
        for (int mt = 0; mt < 4; ++mt) {
            int b0 = mt * 16 + q * 4;
            f32x4 vv = accv[mt][nt];
            #pragma unroll
            for (int r = 0; r < 4; ++r) {
                ob[(size_t)(b0 + r) * 262144 + sl] = __logf(vv[r]) - ld;
            }
        }
    }
}

extern "C" void kernel_launch(void* const* d_in, const int* in_sizes, int n_in,
                              void* d_out, int out_size, void* d_ws, size_t ws_size,
                              hipStream_t stream) {
    const float* x   = (const float*)d_in[0];   // [64,32,32,256]
    const float* acc = (const float*)d_in[1];   // [32,32,256,256]
    float* out = (float*)d_out;                 // [64,32,32,256]
    logmm_kernel<<<dim3(2048), dim3(256), 0, stream>>>(x, acc, out);
}

// Round 3
// 415.257 us; speedup vs baseline: 1.0110x; 1.0110x over previous
//
#include <hip/hip_runtime.h>

// Local2DSum: out[b,v,h,s] = log(sum_c exp(x[b,v,h,c]) * exp(acc[v,h,c,s]))
//                          - log(sum_c exp(acc[v,h,c,s]))
// B=64, V=32, H=32, C=256, S=256. Inputs N(0,1) -> exp safe in fp16.
//
// R3: same pipelined MFMA core as R2 (2 blocks per (v,h), 128 S-cols each,
// ping-pong Bsm, register prefetch of acc). New epilogue: fold denom in as
// a multiply (1/denom), transpose the C-tile through LDS, store contiguous
// 512 B float4 rows (2 full rows per wave per store instr).

typedef _Float16 f16x8 __attribute__((ext_vector_type(8)));
typedef _Float16 f16x2 __attribute__((ext_vector_type(2)));
typedef float f32x4 __attribute__((ext_vector_type(4)));

constexpr int BPITCH = 40;            // f16 per Bsm row (80 B)
constexpr int BBUF   = 128 * BPITCH;  // f16 per buffer (10240 B)

__global__ __launch_bounds__(256, 3)
void logmm_kernel(const float* __restrict__ x,
                  const float* __restrict__ acc,
                  float* __restrict__ out) {
    __shared__ __align__(16) unsigned char smem[53248];   // 52 KB
    _Float16* Asm = (_Float16*)smem;              // 32 KB: exp(x) f16, swizzled
    _Float16* Bsm = (_Float16*)(smem + 32768);    // 20 KB: exp(acc)^T ping-pong
    float*    Tsm = (float*)smem;                 // epilogue overlay [s 0..127][pitch 65]
    float*    red = (float*)(smem + 40960);       // 256 f32 partial denoms
    float*    inv = red + 256;                    // 128 f32 1/denom

    const int tid   = threadIdx.x;        // 0..255
    const int vh    = blockIdx.x >> 1;    // 0..1023
    const int sbase = (blockIdx.x & 1) * 128;

    const float* xb = x   + (size_t)vh * 256;            // b-stride 262144
    const float* ab = acc + (size_t)vh * 65536 + sbase;  // [c][s-local]
    float*       ob = out + (size_t)vh * 256 + sbase;    // b-stride 262144

    // ---- stage A = exp(x) as f16 into LDS (once), XOR-swizzled 16B blocks ----
    {
        const int half = tid >> 7;
        const int c2   = (tid & 127) * 2;
        const int blk  = c2 >> 3;
        #pragma unroll
        for (int it = 0; it < 32; ++it) {
            int row = it * 2 + half;
            float2 v = *(const float2*)(xb + (size_t)row * 262144 + c2);
            f16x2 pk;
            pk.x = (_Float16)__expf(v.x);
            pk.y = (_Float16)__expf(v.y);
            int pb = blk ^ (row & 7);
            *(f16x2*)(Asm + row * 256 + pb * 8 + (c2 & 7)) = pk;
        }
    }

    const int w  = tid >> 6;              // wave -> s-slice base w*32
    const int l  = tid & 63;
    const int ln = l & 15;
    const int q  = l >> 4;

    const int col   = tid & 127;          // local s column this thread stages
    const int khalf = (tid >> 7) * 16;    // k sub-range 0..15 or 16..31

    f32x4 accv[4][2];
    #pragma unroll
    for (int mt = 0; mt < 4; ++mt)
        #pragma unroll
        for (int nt = 0; nt < 2; ++nt)
            accv[mt][nt] = (f32x4){0.f, 0.f, 0.f, 0.f};

    float csum = 0.f;    // partial denom for column `col` over this thread's k rows
    float cur[16], nxt[16];

    // preload chunk 0
    #pragma unroll
    for (int i = 0; i < 16; ++i)
        cur[i] = ab[(size_t)(khalf + i) * 256 + col];

    #pragma unroll
    for (int ch = 0; ch < 8; ++ch) {
        // prefetch next chunk (in flight across exp/pack/barrier/MFMA)
        if (ch < 7) {
            const int c0n = (ch + 1) * 32;
            #pragma unroll
            for (int i = 0; i < 16; ++i)
                nxt[i] = ab[(size_t)(c0n + khalf + i) * 256 + col];
        }
        // process current chunk -> Bsm[buf]
        _Float16* Bb = Bsm + (ch & 1) * BBUF;
        #pragma unroll
        for (int g = 0; g < 2; ++g) {
            f16x8 pk;
            #pragma unroll
            for (int i = 0; i < 8; ++i) {
                float e = __expf(cur[g * 8 + i]);
                csum += e;
                pk[i] = (_Float16)e;
            }
            int G  = (khalf >> 3) + g;               // logical k-group 0..3
            int pg = G ^ ((col >> 2) & 3);           // XOR swizzle
            *(f16x8*)(Bb + col * BPITCH + pg * 8) = pk;
        }
        __syncthreads();   // single barrier: writes visible; prior buf reads reg-complete
        // ---- MFMA step (K=32) ----
        f16x8 bf[2];
        #pragma unroll
        for (int nt = 0; nt < 2; ++nt) {
            int s  = w * 32 + nt * 16 + ln;
            int pg = q ^ ((s >> 2) & 3);
            bf[nt] = *(const f16x8*)(Bb + s * BPITCH + pg * 8);
        }
        f16x8 af[4];
        const int blk = ch * 4 + q;
        #pragma unroll
        for (int mt = 0; mt < 4; ++mt) {
            int r  = mt * 16 + ln;
            int pb = blk ^ (r & 7);
            af[mt] = *(const f16x8*)(Asm + r * 256 + pb * 8);
        }
        #pragma unroll
        for (int mt = 0; mt < 4; ++mt)
            #pragma unroll
            for (int nt = 0; nt < 2; ++nt)
                accv[mt][nt] = __builtin_amdgcn_mfma_f32_16x16x32_f16(
                    af[mt], bf[nt], accv[mt][nt], 0, 0, 0);
        #pragma unroll
        for (int i = 0; i < 16; ++i) cur[i] = nxt[i];
    }

    // ---- denom: reduce the two k-half partials per column -> 1/denom ----
    __syncthreads();                       // all MFMA LDS reads done
    red[tid] = csum;
    __syncthreads();
    if (tid < 128) inv[tid] = 1.0f / (red[tid] + red[tid + 128]);
    __syncthreads();

    // ---- stage C-tile * inv_den into Tsm[s][b] (pitch 65) ----
    #pragma unroll
    for (int nt = 0; nt < 2; ++nt) {
        int sl = w * 32 + nt * 16 + ln;
        float invd = inv[sl];
        #pragma unroll
        for (int mt = 0; mt < 4; ++mt) {
            int b0 = mt * 16 + q * 4;
            f32x4 vv = accv[mt][nt];
            #pragma unroll
            for (int r = 0; r < 4; ++r)
                Tsm[sl * 65 + b0 + r] = vv[r] * invd;
        }
    }
    __syncthreads();

    // ---- coalesced store: each 32-thread group emits one full 512 B row ----
    const int bq = tid >> 5;      // 0..7
    const int cc = tid & 31;
    const int s0 = cc * 4;
    #pragma unroll
    for (int p = 0; p < 8; ++p) {
        int b = p * 8 + bq;
        float4 o;
        o.x = __logf(Tsm[(s0 + 0) * 65 + b]);
        o.y = __logf(Tsm[(s0 + 1) * 65 + b]);
        o.z = __logf(Tsm[(s0 + 2) * 65 + b]);
        o.w = __logf(Tsm[(s0 + 3) * 65 + b]);
        *(float4*)(ob + (size_t)b * 262144 + s0) = o;
    }
}

extern "C" void kernel_launch(void* const* d_in, const int* in_sizes, int n_in,
                              void* d_out, int out_size, void* d_ws, size_t ws_size,
                              hipStream_t stream) {
    const float* x   = (const float*)d_in[0];   // [64,32,32,256]
    const float* acc = (const float*)d_in[1];   // [32,32,256,256]
    float* out = (float*)d_out;                 // [64,32,32,256]
    logmm_kernel<<<dim3(2048), dim3(256), 0, stream>>>(x, acc, out);
}